// Round 5
// baseline (120.230 us; speedup 1.0000x reference)
//
#include <hip/hip_runtime.h>
#include <hip/hip_bf16.h>

typedef __attribute__((ext_vector_type(8))) short bs8;
typedef __attribute__((ext_vector_type(4))) short bs4;
typedef __attribute__((ext_vector_type(4))) float f32x4;

#define HID 64
#define FEATN 32
#define NT 16   // tiles of 16 samples per wave

static __device__ __forceinline__ short f2bf(float f) {
    __hip_bfloat16 h = __float2bfloat16(f);
    return __builtin_bit_cast(short, h);
}

#if defined(__HIP_DEVICE_COMPILE__)
#define MFMA16(a, b, c) __builtin_amdgcn_mfma_f32_16x16x16bf16_1k(a, b, c, 0, 0, 0)
#else
#define MFMA16(a, b, c) (c)
#endif

// Layer 1 (transposed): h^T = W1^T x feats^T via 4x mfma_f32_16x16x32_bf16;
// C-layout (lane holds h[16j+4g+r][sample=row]) IS the B-frag of 16x16x16.
// Layer 2: 4 chained mfma_16x16x16_bf16 with A = W2^T (rows>=4 zero),
// b2 in C-init; outputs land on g==0 lanes.
// Software pipeline, per-wave MLP = 3 table gathers in flight:
//   step t: issue gather(t+3) | load pos(t+5) | compute(t)
// 4 named pos buffers (lead 2..5) + 4 named gather buffers, static indexing.
__global__ __launch_bounds__(256, 4) void plen_fused(
    const float* __restrict__ pos,
    const float* __restrict__ table,
    const float* __restrict__ W1,
    const float* __restrict__ b1,
    const float* __restrict__ W2,
    const float* __restrict__ b2,
    float* __restrict__ out,
    int batch)
{
    const int lane = threadIdx.x & 63;
    const int row  = lane & 15;
    const int g    = lane >> 4;

    // ---- static weight fragments ----
    bs8   w1f[4];
    f32x4 bias1v[4];
    bs4   w2tf[4];
#pragma unroll
    for (int j = 0; j < 4; ++j) {
#pragma unroll
        for (int i = 0; i < 8; ++i)
            w1f[j][i] = f2bf(W1[(g * 8 + i) * HID + j * 16 + row]);
        bias1v[j] = *(const f32x4*)(b1 + j * 16 + g * 4);
#pragma unroll
        for (int i = 0; i < 4; ++i)
            w2tf[j][i] = (row < 4) ? f2bf(W2[(j * 16 + g * 4 + i) * 4 + row]) : (short)0;
    }
    f32x4 oinit;
    if (g == 0) oinit = *(const f32x4*)b2;
    else        oinit = (f32x4){0.f, 0.f, 0.f, 0.f};

    const int wave_id = blockIdx.x * 4 + (threadIdx.x >> 6);
    const int chunk   = wave_id * (NT * 16);
    const size_t dns_base = (size_t)batch * 3;

    auto compute = [&](int sbase, f32x4 f0, f32x4 f1) {
        bs8 af;
        af[0] = f2bf(f0[0]); af[1] = f2bf(f0[1]);
        af[2] = f2bf(f0[2]); af[3] = f2bf(f0[3]);
        af[4] = f2bf(f1[0]); af[5] = f2bf(f1[1]);
        af[6] = f2bf(f1[2]); af[7] = f2bf(f1[3]);

        f32x4 acc[4];
#pragma unroll
        for (int j = 0; j < 4; ++j)
            acc[j] = __builtin_amdgcn_mfma_f32_16x16x32_bf16(w1f[j], af, bias1v[j], 0, 0, 0);

        f32x4 oacc = oinit;
#pragma unroll
        for (int j = 0; j < 4; ++j) {
            bs4 pf;
            pf[0] = f2bf(fmaxf(acc[j][0], 0.0f));
            pf[1] = f2bf(fmaxf(acc[j][1], 0.0f));
            pf[2] = f2bf(fmaxf(acc[j][2], 0.0f));
            pf[3] = f2bf(fmaxf(acc[j][3], 0.0f));
            oacc = MFMA16(w2tf[j], pf, oacc);
        }

        const float r0 = __builtin_amdgcn_rcpf(1.0f + __expf(-oacc[0]));
        const float r1 = __builtin_amdgcn_rcpf(1.0f + __expf(-oacc[1]));
        const float r2 = __builtin_amdgcn_rcpf(1.0f + __expf(-oacc[2]));
        const float dv = oacc[3];
        const float dn = fmaxf(dv, 0.0f) + __logf(1.0f + __expf(-fabsf(dv)));

        if (g == 0) {
            const int s = sbase + row;
            float* rp = out + (size_t)s * 3;
            __builtin_nontemporal_store(r0, rp);
            __builtin_nontemporal_store(r1, rp + 1);
            __builtin_nontemporal_store(r2, rp + 2);
            __builtin_nontemporal_store(dn, out + dns_base + s);
        }
    };

    // ---- pipelined buffers (all names static; no runtime-indexed arrays) ----
    float Px0, Py0, Pz0, Px1, Py1, Pz1, Px2, Py2, Pz2, Px3, Py3, Pz3;
    f32x4 Ga0, Gb0, Ga1, Gb1, Ga2, Gb2, Ga3, Gb3;

#define LOADPOS(t, i) do {                                               \
        const int tt_ = (t) < NT ? (t) : NT - 1;                         \
        const float* pp_ = pos + (size_t)(chunk + tt_ * 16 + row) * 3;   \
        Px##i = pp_[0]; Py##i = pp_[1]; Pz##i = pp_[2];                  \
    } while (0)

#define GATHER(i) do {                                                   \
        const unsigned ix_ = (unsigned)(int)(Px##i * 128.0f);            \
        const unsigned iy_ = (unsigned)(int)(Py##i * 128.0f);            \
        const unsigned iz_ = (unsigned)(int)(Pz##i * 128.0f);            \
        const unsigned flat_ = (ix_ << 14) | (iy_ << 7) | iz_;           \
        const float* rp_ = table + (size_t)flat_ * FEATN + g * 8;        \
        Ga##i = *(const f32x4*)rp_;                                      \
        Gb##i = *(const f32x4*)(rp_ + 4);                                \
    } while (0)

#define STEP(t, gp, lp, cb) do {                                         \
        GATHER(gp);                                                      \
        LOADPOS((t) + 5, lp);                                            \
        compute(chunk + (t) * 16, Ga##cb, Gb##cb);                       \
    } while (0)

    // prologue: pos(0..4) loaded, gathers 0..2 in flight
    LOADPOS(0, 0); LOADPOS(1, 1); LOADPOS(2, 2); LOADPOS(3, 3);
    GATHER(0); GATHER(1); GATHER(2);
    LOADPOS(4, 0);

    for (int t = 0; t < NT; t += 4) {
        STEP(t + 0, 3, 1, 0);
        STEP(t + 1, 0, 2, 1);
        STEP(t + 2, 1, 3, 2);
        STEP(t + 3, 2, 0, 3);
    }
#undef STEP
#undef GATHER
#undef LOADPOS
}

extern "C" void kernel_launch(void* const* d_in, const int* in_sizes, int n_in,
                              void* d_out, int out_size, void* d_ws, size_t ws_size,
                              hipStream_t stream) {
    const float* pos   = (const float*)d_in[0];
    const float* table = (const float*)d_in[1];
    const float* W1    = (const float*)d_in[2];
    const float* b1    = (const float*)d_in[3];
    const float* W2    = (const float*)d_in[4];
    const float* b2    = (const float*)d_in[5];
    float* out = (float*)d_out;

    const int batch  = in_sizes[0] / 3;            // 4,194,304
    const int blocks = batch / (4 * NT * 16);      // 4096
    hipLaunchKernelGGL(plen_fused, dim3(blocks), dim3(256), 0, stream,
                       pos, table, W1, b1, W2, b2, out, batch);
}